// Round 3
// baseline (11.380 us; speedup 1.0000x reference)
//
#include <hip/hip_runtime.h>

// HWnet: per-sample nearest-entry lookup in a sorted 1024-entry grid,
// then a 17-wide sharpened softmax over the neighboring window,
// then a weighted sum of vector_table (V=1).
//
// N=262144, T=1024, E=8, V=1. ~2MB real traffic -> latency/launch bound.
//
// Round-3 change: the 10-step dependent binary search (10 serial ds_read,
// ~1200cy) is replaced by a 3-stage COUNTING search using
// lower_bound(x) == #{i : eval[i] < x}:
//   A: 31 uniform pivots eval[32k], preloaded from global (scalar loads,
//      overlap with LDS staging) -> pure VALU, span 1024 -> 32.
//   B: 7 independent LDS reads (one latency batch), span 32 -> 4.
//   C: one aligned ds_read_b128 + 4 compares, span 4 -> exact.
// Memory chain: ~240cy instead of ~1200cy.

constexpr int T_SIZE = 1024;
constexpr int E_SIZE = 8;
constexpr int WIN    = 2 * E_SIZE + 1;   // 17
constexpr int BLOCK  = 256;

__device__ __forceinline__ float hwnet_finish(
    float x, int lo,
    const float2* __restrict__ s_ev,
    const float* __restrict__ s_take)
{
    // Nearest entry, replicating jnp.argmin((x-e)^2) semantics:
    // squares in f32, ties -> FIRST (lowest) index.
    int idx;
    if (lo == 0) {
        idx = 0;
    } else if (lo == T_SIZE) {
        idx = T_SIZE - 1;
    } else {
        const float d0 = x - s_ev[lo - 1].x;
        const float d1 = x - s_ev[lo].x;
        idx = (d0 * d0 <= d1 * d1) ? (lo - 1) : lo;
    }
    // Walk down through rounded-square ties / duplicates -> first minimum.
    while (idx > 0) {
        const float dp = x - s_ev[idx - 1].x;
        const float dc = x - s_ev[idx].x;
        if (dp * dp <= dc * dc) --idx; else break;
    }

    const float take = s_take[idx];

    int c = idx;
    if (c < E_SIZE) c = E_SIZE;
    if (c > T_SIZE - 1 - E_SIZE) c = T_SIZE - 1 - E_SIZE;
    const int base = c - E_SIZE;

    // Scores -(d^2)*take <= 0 -> exp in (0,1]; no max-subtraction needed.
    float sum = 0.0f, acc = 0.0f;
    #pragma unroll
    for (int k = 0; k < WIN; ++k) {
        const float2 ev = s_ev[base + k];
        const float d = x - ev.x;
        const float e = __expf(-(d * d) * take);
        sum += e;
        acc += e * ev.y;
    }
    return acc / sum;
}

__global__ __launch_bounds__(BLOCK) void hwnet_kernel(
    const float* __restrict__ inputs,
    const float* __restrict__ eval_t,
    const float* __restrict__ take_t,
    const float* __restrict__ vec_t,
    float* __restrict__ out,
    int n)
{
    __shared__ alignas(16) float s_evf[T_SIZE];   // flat eval (stages B/C)
    __shared__ float2 s_ev[T_SIZE];               // (eval, vec) (window)
    __shared__ float  s_take[T_SIZE];

    // Stage-A pivots: uniform addresses, independent of LDS staging ->
    // scalar loads that overlap the staging latency.
    float pA[31];
    #pragma unroll
    for (int k = 0; k < 31; ++k) pA[k] = eval_t[(k + 1) << 5];

    // Vectorized stage: 256 threads x 4 entries = 1024.
    {
        const int i4 = threadIdx.x * 4;
        const float4 e4 = *reinterpret_cast<const float4*>(eval_t + i4);
        const float4 t4 = *reinterpret_cast<const float4*>(take_t + i4);
        const float4 v4 = *reinterpret_cast<const float4*>(vec_t + i4);
        *reinterpret_cast<float4*>(s_evf + i4) = e4;
        const float ee[4] = {e4.x, e4.y, e4.z, e4.w};
        const float tt[4] = {t4.x, t4.y, t4.z, t4.w};
        const float vv[4] = {v4.x, v4.y, v4.z, v4.w};
        #pragma unroll
        for (int k = 0; k < 4; ++k) {
            const int i = i4 + k;
            s_ev[i] = make_float2(ee[k], vv[k]);
            s_take[i] = tt[k];
        }
    }
    __syncthreads();

    const int gid2 = blockIdx.x * BLOCK + threadIdx.x;
    const int n2 = n >> 1;
    if (gid2 < n2) {
        const float2 x2 = reinterpret_cast<const float2*>(inputs)[gid2];

        // ---- Stage A: span 1024 -> 32 (pure VALU, pivots in regs).
        int c0 = 0, c1 = 0;
        #pragma unroll
        for (int k = 0; k < 31; ++k) {
            c0 += (pA[k] < x2.x) ? 1 : 0;
            c1 += (pA[k] < x2.y) ? 1 : 0;
        }
        int b0 = c0 << 5, b1 = c1 << 5;

        // ---- Stage B: span 32 -> 4 (7 independent LDS reads, one batch).
        float qb0[7], qb1[7];
        #pragma unroll
        for (int k = 0; k < 7; ++k) {
            qb0[k] = s_evf[b0 + ((k + 1) << 2)];
            qb1[k] = s_evf[b1 + ((k + 1) << 2)];
        }
        int d0 = 0, d1 = 0;
        #pragma unroll
        for (int k = 0; k < 7; ++k) {
            d0 += (qb0[k] < x2.x) ? 1 : 0;
            d1 += (qb1[k] < x2.y) ? 1 : 0;
        }
        b0 += d0 << 2;
        b1 += d1 << 2;

        // ---- Stage C: span 4 -> exact lower_bound (aligned b128 reads).
        const float4 q0 = *reinterpret_cast<const float4*>(s_evf + b0);
        const float4 q1 = *reinterpret_cast<const float4*>(s_evf + b1);
        const int lo0 = b0 + ((q0.x < x2.x) ? 1 : 0) + ((q0.y < x2.x) ? 1 : 0)
                           + ((q0.z < x2.x) ? 1 : 0) + ((q0.w < x2.x) ? 1 : 0);
        const int lo1 = b1 + ((q1.x < x2.y) ? 1 : 0) + ((q1.y < x2.y) ? 1 : 0)
                           + ((q1.z < x2.y) ? 1 : 0) + ((q1.w < x2.y) ? 1 : 0);

        const float r0 = hwnet_finish(x2.x, lo0, s_ev, s_take);
        const float r1 = hwnet_finish(x2.y, lo1, s_ev, s_take);
        reinterpret_cast<float2*>(out)[gid2] = make_float2(r0, r1);
    }

    // Odd-n tail (dead for N=262144, kept for safety).
    if ((n & 1) && gid2 == 0) {
        const float x = inputs[n - 1];
        int lo = 0, hi = T_SIZE;
        for (int it = 0; it < 10; ++it) {
            const int mid = (lo + hi) >> 1;
            if (s_evf[mid] < x) lo = mid + 1; else hi = mid;
        }
        out[n - 1] = hwnet_finish(x, lo, s_ev, s_take);
    }
}

extern "C" void kernel_launch(void* const* d_in, const int* in_sizes, int n_in,
                              void* d_out, int out_size, void* d_ws, size_t ws_size,
                              hipStream_t stream) {
    const float* inputs = (const float*)d_in[0];
    const float* eval_t = (const float*)d_in[1];
    const float* take_t = (const float*)d_in[2];
    const float* vec_t  = (const float*)d_in[3];
    float* out = (float*)d_out;

    const int n = in_sizes[0];                       // N
    const int n2 = n >> 1;
    const int grid = (n2 + BLOCK - 1) / BLOCK;       // 512 blocks
    hwnet_kernel<<<grid, BLOCK, 0, stream>>>(inputs, eval_t, take_t, vec_t, out, n);
}

// Round 4
// 10.972 us; speedup vs baseline: 1.0371x; 1.0371x over previous
//
#include <hip/hip_runtime.h>

// HWnet: per-sample nearest-entry lookup in a sorted 1024-entry grid,
// then a 17-wide sharpened softmax over the neighboring window,
// then a weighted sum of vector_table (V=1).
//
// N=262144, T=1024, E=8, V=1. ~2MB real traffic -> latency/launch bound.
//
// Round-4 changes (round-3 counting search kept):
//  - input load issued BEFORE table staging: its ~900cy HBM latency now
//    hides under the staging loads instead of sitting exposed after the
//    barrier (compiler cannot hoist a guarded load across __syncthreads).
//  - 1 sample/thread, BLOCK=512, 512 blocks -> 2 blocks/CU x 8 waves =
//    16 waves/CU (4/SIMD), doubling TLP vs round 3; per-thread serial
//    work halves; staging traffic unchanged.

constexpr int T_SIZE = 1024;
constexpr int E_SIZE = 8;
constexpr int WIN    = 2 * E_SIZE + 1;   // 17
constexpr int BLOCK  = 512;

__device__ __forceinline__ float hwnet_finish(
    float x, int lo,
    const float2* __restrict__ s_ev,
    const float* __restrict__ s_take)
{
    // Nearest entry, replicating jnp.argmin((x-e)^2) semantics:
    // squares in f32, ties -> FIRST (lowest) index.
    int idx;
    if (lo == 0) {
        idx = 0;
    } else if (lo == T_SIZE) {
        idx = T_SIZE - 1;
    } else {
        const float d0 = x - s_ev[lo - 1].x;
        const float d1 = x - s_ev[lo].x;
        idx = (d0 * d0 <= d1 * d1) ? (lo - 1) : lo;
    }
    // Walk down through rounded-square ties / duplicates -> first minimum.
    while (idx > 0) {
        const float dp = x - s_ev[idx - 1].x;
        const float dc = x - s_ev[idx].x;
        if (dp * dp <= dc * dc) --idx; else break;
    }

    const float take = s_take[idx];

    int c = idx;
    if (c < E_SIZE) c = E_SIZE;
    if (c > T_SIZE - 1 - E_SIZE) c = T_SIZE - 1 - E_SIZE;
    const int base = c - E_SIZE;

    // Scores -(d^2)*take <= 0 -> exp in (0,1]; no max-subtraction needed.
    float sum = 0.0f, acc = 0.0f;
    #pragma unroll
    for (int k = 0; k < WIN; ++k) {
        const float2 ev = s_ev[base + k];
        const float d = x - ev.x;
        const float e = __expf(-(d * d) * take);
        sum += e;
        acc += e * ev.y;
    }
    return acc / sum;
}

__global__ __launch_bounds__(BLOCK) void hwnet_kernel(
    const float* __restrict__ inputs,
    const float* __restrict__ eval_t,
    const float* __restrict__ take_t,
    const float* __restrict__ vec_t,
    float* __restrict__ out,
    int n)
{
    __shared__ alignas(16) float s_evf[T_SIZE];   // flat eval (stages B/C)
    __shared__ float2 s_ev[T_SIZE];               // (eval, vec) (window)
    __shared__ float  s_take[T_SIZE];

    const int gid = blockIdx.x * BLOCK + threadIdx.x;

    // ---- Input load FIRST: hide its HBM latency under table staging.
    float x = 0.0f;
    if (gid < n) x = inputs[gid];

    // Stage-A pivots: uniform addresses -> scalar loads, overlap staging.
    float pA[31];
    #pragma unroll
    for (int k = 0; k < 31; ++k) pA[k] = eval_t[(k + 1) << 5];

    // Vectorized stage: 512 threads x 2 entries = 1024.
    {
        const int i2 = threadIdx.x * 2;
        const float2 e2 = *reinterpret_cast<const float2*>(eval_t + i2);
        const float2 t2 = *reinterpret_cast<const float2*>(take_t + i2);
        const float2 v2 = *reinterpret_cast<const float2*>(vec_t + i2);
        *reinterpret_cast<float2*>(s_evf + i2) = e2;
        s_ev[i2]     = make_float2(e2.x, v2.x);
        s_ev[i2 + 1] = make_float2(e2.y, v2.y);
        s_take[i2]     = t2.x;
        s_take[i2 + 1] = t2.y;
    }
    __syncthreads();

    if (gid < n) {
        // ---- Stage A: span 1024 -> 32 (pure VALU, pivots in regs).
        int c0 = 0;
        #pragma unroll
        for (int k = 0; k < 31; ++k) c0 += (pA[k] < x) ? 1 : 0;
        int b = c0 << 5;

        // ---- Stage B: span 32 -> 4 (7 independent LDS reads, one batch).
        float qb[7];
        #pragma unroll
        for (int k = 0; k < 7; ++k) qb[k] = s_evf[b + ((k + 1) << 2)];
        int d = 0;
        #pragma unroll
        for (int k = 0; k < 7; ++k) d += (qb[k] < x) ? 1 : 0;
        b += d << 2;

        // ---- Stage C: span 4 -> exact lower_bound (aligned b128 read).
        const float4 q = *reinterpret_cast<const float4*>(s_evf + b);
        const int lo = b + ((q.x < x) ? 1 : 0) + ((q.y < x) ? 1 : 0)
                         + ((q.z < x) ? 1 : 0) + ((q.w < x) ? 1 : 0);

        out[gid] = hwnet_finish(x, lo, s_ev, s_take);
    }
}

extern "C" void kernel_launch(void* const* d_in, const int* in_sizes, int n_in,
                              void* d_out, int out_size, void* d_ws, size_t ws_size,
                              hipStream_t stream) {
    const float* inputs = (const float*)d_in[0];
    const float* eval_t = (const float*)d_in[1];
    const float* take_t = (const float*)d_in[2];
    const float* vec_t  = (const float*)d_in[3];
    float* out = (float*)d_out;

    const int n = in_sizes[0];                       // N
    const int grid = (n + BLOCK - 1) / BLOCK;        // 512 blocks
    hwnet_kernel<<<grid, BLOCK, 0, stream>>>(inputs, eval_t, take_t, vec_t, out, n);
}